// Round 4
// baseline (128.016 us; speedup 1.0000x reference)
//
#include <hip/hip_runtime.h>
#include <hip/hip_bf16.h>

// Problem constants
#define BATCH 2
#define SEQ   2048
#define EMBD  1024
#define NHEAD 16
#define HDIM  64
#define N3    3072           // 3*EMBD
#define MTOT  4096           // BATCH*SEQ
#define KDIM  1024

typedef __attribute__((ext_vector_type(8))) short  short8;   // 8 x bf16 (4 VGPRs)
typedef __attribute__((ext_vector_type(4))) short  s16x4;
typedef __attribute__((ext_vector_type(4))) unsigned short u16x4;
typedef __attribute__((ext_vector_type(4))) float  f32x4;

__device__ __forceinline__ unsigned short f2bf(float f) {
    unsigned int u = __builtin_bit_cast(unsigned int, f);
    u += 0x7fffu + ((u >> 16) & 1u);          // RNE
    return (unsigned short)(u >> 16);
}

// ---------------------------------------------------------------- cast x -> bf16
__global__ __launch_bounds__(256) void cast_x_kernel(const float* __restrict__ x,
                                                     short* __restrict__ xb, int n4) {
    int i = blockIdx.x * 256 + threadIdx.x;
    if (i >= n4) return;
    float4 f = reinterpret_cast<const float4*>(x)[i];
    s16x4 o;
    o[0] = (short)f2bf(f.x); o[1] = (short)f2bf(f.y);
    o[2] = (short)f2bf(f.z); o[3] = (short)f2bf(f.w);
    reinterpret_cast<s16x4*>(xb)[i] = o;
}

// ------------------------------------------- cast + transpose w [K,N3] -> wt [N3,K]
__global__ __launch_bounds__(256) void cast_wt_kernel(const float* __restrict__ w,
                                                      short* __restrict__ wt) {
    __shared__ float tile[32][33];
    int n0 = blockIdx.x * 32;   // N3/32 = 96
    int k0 = blockIdx.y * 32;   // K/32  = 32
    int tx = threadIdx.x & 31;
    int ty = threadIdx.x >> 5;  // 0..7
#pragma unroll
    for (int i = 0; i < 4; ++i)
        tile[ty + i * 8][tx] = w[(size_t)(k0 + ty + i * 8) * N3 + n0 + tx];
    __syncthreads();
#pragma unroll
    for (int i = 0; i < 4; ++i)
        wt[(size_t)(n0 + ty + i * 8) * KDIM + k0 + tx] = (short)f2bf(tile[tx][ty + i * 8]);
}

// ---------------------------------------------------------------- QKV GEMM
// C[m,n] = sum_k xb[m,k] * wt[n,k];  M=4096, N=3072, K=1024
__device__ __forceinline__ void stage_tile(const short* gbase, short* lbase, int tid) {
#pragma unroll
    for (int c = 0; c < 2; ++c) {
        int row = c * 64 + (tid >> 2);
        int chunk = tid & 3;
        const short* gp = gbase + (size_t)row * KDIM + chunk * 8;
        short* lp = lbase + c * 2048 + tid * 8;   // bytes: c*4096 + tid*16
        __builtin_amdgcn_global_load_lds((const __attribute__((address_space(1))) void*)gp,
                                         (__attribute__((address_space(3))) void*)lp,
                                         16, 0, 0);
    }
}

__global__ __launch_bounds__(256) void qkv_gemm_kernel(const short* __restrict__ xb,
                                                       const short* __restrict__ wt,
                                                       short* __restrict__ qb,
                                                       short* __restrict__ kbuf,
                                                       short* __restrict__ vt) {
    __shared__ short lA[2][128 * 32];
    __shared__ short lB[2][128 * 32];

    const int tid  = threadIdx.x;
    const int lane = tid & 63;
    const int wid  = tid >> 6;
    const int wm = wid >> 1, wn = wid & 1;
    const int m0 = blockIdx.y * 128;
    const int n0 = blockIdx.x * 128;

    f32x4 acc[4][4];
#pragma unroll
    for (int i = 0; i < 4; ++i)
#pragma unroll
        for (int j = 0; j < 4; ++j) acc[i][j] = (f32x4){0.f, 0.f, 0.f, 0.f};

    const short* gA = xb + (size_t)m0 * KDIM;
    const short* gB = wt + (size_t)n0 * KDIM;

    stage_tile(gA, lA[0], tid);
    stage_tile(gB, lB[0], tid);
    asm volatile("s_waitcnt vmcnt(0)" ::: "memory");
    __syncthreads();

    int cur = 0;
    const int arow = (lane & 15) * 32 + (lane >> 4) * 8;
#pragma unroll 1
    for (int kt = 0; kt < KDIM / 32; ++kt) {
        if (kt + 1 < KDIM / 32) {
            stage_tile(gA + (kt + 1) * 32, lA[cur ^ 1], tid);
            stage_tile(gB + (kt + 1) * 32, lB[cur ^ 1], tid);
        }
        short8 a[4], b[4];
#pragma unroll
        for (int im = 0; im < 4; ++im)
            a[im] = *(const short8*)&lA[cur][(wm * 64 + im * 16) * 32 + arow];
#pragma unroll
        for (int in = 0; in < 4; ++in)
            b[in] = *(const short8*)&lB[cur][(wn * 64 + in * 16) * 32 + arow];
#pragma unroll
        for (int im = 0; im < 4; ++im)
#pragma unroll
            for (int in = 0; in < 4; ++in)
                acc[im][in] = __builtin_amdgcn_mfma_f32_16x16x32_bf16(a[im], b[in], acc[im][in], 0, 0, 0);
        asm volatile("s_waitcnt vmcnt(0)" ::: "memory");
        __syncthreads();
        cur ^= 1;
    }

    // epilogue: scatter to q [B,H,T,D], k [B,H,T,D], v^T [B,H,D,T]
#pragma unroll
    for (int im = 0; im < 4; ++im) {
        int t0m = m0 + wm * 64 + im * 16 + (lane >> 4) * 4;
        int b = t0m >> 11;
        int t0 = t0m & 2047;
#pragma unroll
        for (int in = 0; in < 4; ++in) {
            int col = n0 + wn * 64 + in * 16 + (lane & 15);
            int which = col >> 10;
            int h = (col >> 6) & 15;
            int d = col & 63;
            if (which == 2) {
                u16x4 pk;
#pragma unroll
                for (int r = 0; r < 4; ++r) pk[r] = f2bf(acc[im][in][r]);
                *(u16x4*)&vt[((size_t)(b * NHEAD + h) * HDIM + d) * SEQ + t0] = pk;
            } else {
                short* dst = (which == 0) ? qb : kbuf;
#pragma unroll
                for (int r = 0; r < 4; ++r)
                    dst[((size_t)(b * NHEAD + h) * SEQ + t0 + r) * HDIM + d] = (short)f2bf(acc[im][in][r]);
            }
        }
    }
}

// ---------------------------------------------------------------- flash attention
// grid (32, B*H), 128 threads = 2 waves, 16 q-rows each (32 rows/block).
// Fold: block pid handles sub-q-tiles {63-pid, pid} (32 rows each) -> uniform
// 33 kv-tile iterations per block; 1024 blocks = 4/CU co-resident.
// K/V double-buffered LDS (KVB=64), XOR-swizzled, counted vmcnt.
#define KVB 64

__device__ __forceinline__ void stage_kv(const short* kh, const short* vh, int kb,
                                         short* lk, short* lv, int tid) {
#pragma unroll
    for (int c = 0; c < 4; ++c) {
        int row = c * 16 + (tid >> 3);               // 0..63
        int sch = (tid & 7) ^ (row & 7);             // swizzled 16B-chunk index
        const short* gk = kh + (size_t)(kb + row) * HDIM + sch * 8;
        short* lpk = lk + c * 1024 + tid * 8;        // linear shorts
        __builtin_amdgcn_global_load_lds((const __attribute__((address_space(1))) void*)gk,
                                         (__attribute__((address_space(3))) void*)lpk, 16, 0, 0);
        const short* gv = vh + (size_t)row * SEQ + kb + sch * 8;   // row = d index
        short* lpv = lv + c * 1024 + tid * 8;
        __builtin_amdgcn_global_load_lds((const __attribute__((address_space(1))) void*)gv,
                                         (__attribute__((address_space(3))) void*)lpv, 16, 0, 0);
    }
}

__global__ __launch_bounds__(128) void attn_kernel(const short* __restrict__ q,
                                                   const short* __restrict__ kk,
                                                   const short* __restrict__ vtg,
                                                   float* __restrict__ out) {
    const int tid  = threadIdx.x;
    const int lane = tid & 63;
    const int wid  = tid >> 6;                       // 0..1
    const int pid = blockIdx.x;                      // 0..31
    const int bh = blockIdx.y;
    const int rbase = lane & 15;
    const int hi    = lane >> 4;

    const short* qh = q   + (size_t)bh * SEQ * HDIM;
    const short* kh = kk  + (size_t)bh * SEQ * HDIM;
    const short* vh = vtg + (size_t)bh * HDIM * SEQ;

    __shared__ short lK[2][KVB * 64];
    __shared__ short lV[2][KVB * 64];
    __shared__ short psh[2][16 * 64];
    short* pw = psh[wid];

    const float L2E = 1.4426950408889634f;
    const float C1  = 0.125f * 1.4426950408889634f;   // scale folded into exp2
    short8 vone;
#pragma unroll
    for (int j = 0; j < 8; ++j) vone[j] = (short)0x3F80;   // bf16 1.0

    const int b = bh >> 4, h = bh & 15;

#pragma unroll 1
    for (int seg = 0; seg < 2; ++seg) {
        const int jt = seg ? pid : (63 - pid);       // sub-q-tile (32 rows)
        const int qbase = jt * 32 + wid * 16;

        // Q fragments (A layout: m = lane&15, k = hi*8 + j), two 32-wide k-chunks
        short8 aQ[2];
#pragma unroll
        for (int c = 0; c < 2; ++c)
            aQ[c] = *(const short8*)&qh[(size_t)(qbase + rbase) * HDIM + c * 32 + hi * 8];

        f32x4 o[4];
#pragma unroll
        for (int i = 0; i < 4; ++i) o[i] = (f32x4){0.f, 0.f, 0.f, 0.f};
        float mrun[4] = {-INFINITY, -INFINITY, -INFINITY, -INFINITY};
        float lrun[4] = {0.f, 0.f, 0.f, 0.f};

        const int ktiles = (jt >> 1) + 1;            // ceil((jt*32+32)/64)
        stage_kv(kh, vh, 0, lK[0], lV[0], tid);
        int cur = 0;
#pragma unroll 1
        for (int t = 0; t < ktiles; ++t) {
            const int kb = t * KVB;
            if (t + 1 < ktiles) {
                stage_kv(kh, vh, kb + KVB, lK[cur ^ 1], lV[cur ^ 1], tid);
                asm volatile("s_waitcnt vmcnt(8) lgkmcnt(0)" ::: "memory");
            } else {
                asm volatile("s_waitcnt vmcnt(0) lgkmcnt(0)" ::: "memory");
            }
            __builtin_amdgcn_s_barrier();
            __builtin_amdgcn_sched_barrier(0);

            if (kb < qbase + 16) {   // wave-uniform: tile not fully masked for this wave
                const short* lk = lK[cur];
                const short* lv = lV[cur];
                // ---- QK^T: 4 n-tiles x 2 k-chunks (raw scores, scale folded later)
                f32x4 s[4];
                __builtin_amdgcn_s_setprio(1);
#pragma unroll
                for (int nb = 0; nb < 4; ++nb) {
                    int r = nb * 16 + rbase;
                    f32x4 a = (f32x4){0.f, 0.f, 0.f, 0.f};
#pragma unroll
                    for (int c = 0; c < 2; ++c) {
                        int cc = c * 4 + hi;
                        short8 bK = *(const short8*)&lk[r * 64 + ((cc ^ (r & 7)) * 8)];
                        a = __builtin_amdgcn_mfma_f32_16x16x32_bf16(aQ[c], bK, a, 0, 0, 0);
                    }
                    s[nb] = a;
                }
                __builtin_amdgcn_s_setprio(0);
                // ---- causal mask (diagonal tile only; wave-uniform branch)
                if (kb + KVB - 1 > qbase) {
#pragma unroll
                    for (int nb = 0; nb < 4; ++nb) {
                        int j = kb + nb * 16 + rbase;
#pragma unroll
                        for (int r4 = 0; r4 < 4; ++r4) {
                            int qrow = qbase + hi * 4 + r4;
                            if (j > qrow) s[nb][r4] = -1e30f;
                        }
                    }
                }
                // ---- row max (16-lane groups hold one q-row's 16 keys)
                float pms[4];
                bool grow = false;
#pragma unroll
                for (int r4 = 0; r4 < 4; ++r4) {
                    float pm = fmaxf(fmaxf(s[0][r4], s[1][r4]), fmaxf(s[2][r4], s[3][r4]));
#pragma unroll
                    for (int m = 1; m < 16; m <<= 1) pm = fmaxf(pm, __shfl_xor(pm, m));
                    pms[r4] = pm * 0.125f;
                    grow = grow || (pms[r4] > mrun[r4]);
                }
                // ---- defer-max: rescale only when some row's max grew
                if (__any(grow)) {
#pragma unroll
                    for (int r4 = 0; r4 < 4; ++r4) {
                        float mnew = fmaxf(mrun[r4], pms[r4]);
                        float sf = exp2f((mrun[r4] - mnew) * L2E);
                        mrun[r4] = mnew;
                        lrun[r4] *= sf;
#pragma unroll
                        for (int dt = 0; dt < 4; ++dt) o[dt][r4] *= sf;
                    }
                }
                float mterm[4];
#pragma unroll
                for (int r4 = 0; r4 < 4; ++r4) mterm[r4] = mrun[r4] * L2E;

                // ---- P = exp2(s*C1 - mterm) -> bf16 -> LDS (swizzled)
#pragma unroll
                for (int nb = 0; nb < 4; ++nb)
#pragma unroll
                    for (int r4 = 0; r4 < 4; ++r4) {
                        float p = exp2f(fmaf(s[nb][r4], C1, -mterm[r4]));
                        int prow = hi * 4 + r4;
                        int pcol = nb * 16 + rbase;
                        pw[prow * 64 + (pcol ^ ((prow & 7) << 3))] =
                            __builtin_bit_cast(short, __float2bfloat16(p));
                    }
                asm volatile("s_waitcnt lgkmcnt(0)" ::: "memory");
                __builtin_amdgcn_sched_barrier(0);
                short8 pa[2];
#pragma unroll
                for (int ks = 0; ks < 2; ++ks) {
                    int cc = ks * 4 + hi;
                    pa[ks] = *(const short8*)&pw[rbase * 64 + ((cc ^ (rbase & 7)) * 8)];
                }
                // ---- PV + row-sum via ones-column MFMA
                f32x4 osum = (f32x4){0.f, 0.f, 0.f, 0.f};
                __builtin_amdgcn_s_setprio(1);
#pragma unroll
                for (int dt = 0; dt < 4; ++dt) {
                    int d = dt * 16 + rbase;
#pragma unroll
                    for (int ks = 0; ks < 2; ++ks) {
                        int cc = ks * 4 + hi;
                        short8 bV = *(const short8*)&lv[d * 64 + ((cc ^ (d & 7)) * 8)];
                        o[dt] = __builtin_amdgcn_mfma_f32_16x16x32_bf16(pa[ks], bV, o[dt], 0, 0, 0);
                    }
                }
#pragma unroll
                for (int ks = 0; ks < 2; ++ks)
                    osum = __builtin_amdgcn_mfma_f32_16x16x32_bf16(pa[ks], vone, osum, 0, 0, 0);
                __builtin_amdgcn_s_setprio(0);
#pragma unroll
                for (int r4 = 0; r4 < 4; ++r4) lrun[r4] += osum[r4];
            }
            __builtin_amdgcn_sched_barrier(0);
            __builtin_amdgcn_s_barrier();
            cur ^= 1;
        }

        // write out [B,T,H,D] fp32
#pragma unroll
        for (int r4 = 0; r4 < 4; ++r4) {
            float inv = 1.0f / lrun[r4];
            int tq = qbase + hi * 4 + r4;
#pragma unroll
            for (int dt = 0; dt < 4; ++dt)
                out[((size_t)(b * SEQ + tq) * NHEAD + h) * HDIM + dt * 16 + rbase] = o[dt][r4] * inv;
        }
    }
}

// ---------------------------------------------------------------- launch
extern "C" void kernel_launch(void* const* d_in, const int* in_sizes, int n_in,
                              void* d_out, int out_size, void* d_ws, size_t ws_size,
                              hipStream_t stream) {
    const float* x = (const float*)d_in[0];
    const float* w = (const float*)d_in[1];
    float* out = (float*)d_out;

    char* ws = (char*)d_ws;
    short* xb   = (short*)(ws);                            // 8 MB  [M,K] bf16
    short* wt   = (short*)(ws + (size_t)8  * 1024 * 1024); // 6 MB  [N3,K] bf16
    short* qb   = (short*)(ws + (size_t)14 * 1024 * 1024); // 8 MB  [B,H,T,D]
    short* kbuf = (short*)(ws + (size_t)22 * 1024 * 1024); // 8 MB  [B,H,T,D]
    short* vt   = (short*)(ws + (size_t)30 * 1024 * 1024); // 8 MB  [B,H,D,T]

    cast_x_kernel<<<dim3(MTOT * KDIM / 4 / 256), dim3(256), 0, stream>>>(x, xb, MTOT * KDIM / 4);
    cast_wt_kernel<<<dim3(N3 / 32, KDIM / 32), dim3(256), 0, stream>>>(w, wt);
    qkv_gemm_kernel<<<dim3(N3 / 128, MTOT / 128), dim3(256), 0, stream>>>(xb, wt, qb, kbuf, vt);
    attn_kernel<<<dim3(32, BATCH * NHEAD), dim3(128), 0, stream>>>(qb, kbuf, vt, out);
}

// Round 5
// 109.031 us; speedup vs baseline: 1.1741x; 1.1741x over previous
//
#include <hip/hip_runtime.h>
#include <hip/hip_bf16.h>

// Problem constants
#define BATCH 2
#define SEQ   2048
#define EMBD  1024
#define NHEAD 16
#define HDIM  64
#define N3    3072           // 3*EMBD
#define MTOT  4096           // BATCH*SEQ
#define KDIM  1024

typedef __attribute__((ext_vector_type(8))) short  short8;   // 8 x bf16 (4 VGPRs)
typedef __attribute__((ext_vector_type(4))) short  s16x4;
typedef __attribute__((ext_vector_type(4))) unsigned short u16x4;
typedef __attribute__((ext_vector_type(4))) float  f32x4;

__device__ __forceinline__ unsigned short f2bf(float f) {
    unsigned int u = __builtin_bit_cast(unsigned int, f);
    u += 0x7fffu + ((u >> 16) & 1u);          // RNE
    return (unsigned short)(u >> 16);
}

// ---------------------------------------------------------------- cast x -> bf16
__global__ __launch_bounds__(256) void cast_x_kernel(const float* __restrict__ x,
                                                     short* __restrict__ xb, int n4) {
    int i = blockIdx.x * 256 + threadIdx.x;
    if (i >= n4) return;
    float4 f = reinterpret_cast<const float4*>(x)[i];
    s16x4 o;
    o[0] = (short)f2bf(f.x); o[1] = (short)f2bf(f.y);
    o[2] = (short)f2bf(f.z); o[3] = (short)f2bf(f.w);
    reinterpret_cast<s16x4*>(xb)[i] = o;
}

// ------------------------------------------- cast + transpose w [K,N3] -> wt [N3,K]
__global__ __launch_bounds__(256) void cast_wt_kernel(const float* __restrict__ w,
                                                      short* __restrict__ wt) {
    __shared__ float tile[32][33];
    int n0 = blockIdx.x * 32;   // N3/32 = 96
    int k0 = blockIdx.y * 32;   // K/32  = 32
    int tx = threadIdx.x & 31;
    int ty = threadIdx.x >> 5;  // 0..7
#pragma unroll
    for (int i = 0; i < 4; ++i)
        tile[ty + i * 8][tx] = w[(size_t)(k0 + ty + i * 8) * N3 + n0 + tx];
    __syncthreads();
#pragma unroll
    for (int i = 0; i < 4; ++i)
        wt[(size_t)(n0 + ty + i * 8) * KDIM + k0 + tx] = (short)f2bf(tile[tx][ty + i * 8]);
}

// ---------------------------------------------------------------- QKV GEMM
// C[m,n] = sum_k xb[m,k] * wt[n,k];  M=4096, N=3072, K=1024
__device__ __forceinline__ void stage_tile(const short* gbase, short* lbase, int tid) {
#pragma unroll
    for (int c = 0; c < 2; ++c) {
        int row = c * 64 + (tid >> 2);
        int chunk = tid & 3;
        const short* gp = gbase + (size_t)row * KDIM + chunk * 8;
        short* lp = lbase + c * 2048 + tid * 8;   // bytes: c*4096 + tid*16
        __builtin_amdgcn_global_load_lds((const __attribute__((address_space(1))) void*)gp,
                                         (__attribute__((address_space(3))) void*)lp,
                                         16, 0, 0);
    }
}

__global__ __launch_bounds__(256) void qkv_gemm_kernel(const short* __restrict__ xb,
                                                       const short* __restrict__ wt,
                                                       short* __restrict__ qb,
                                                       short* __restrict__ kbuf,
                                                       short* __restrict__ vt) {
    __shared__ short lA[2][128 * 32];
    __shared__ short lB[2][128 * 32];

    const int tid  = threadIdx.x;
    const int lane = tid & 63;
    const int wid  = tid >> 6;
    const int wm = wid >> 1, wn = wid & 1;
    const int m0 = blockIdx.y * 128;
    const int n0 = blockIdx.x * 128;

    f32x4 acc[4][4];
#pragma unroll
    for (int i = 0; i < 4; ++i)
#pragma unroll
        for (int j = 0; j < 4; ++j) acc[i][j] = (f32x4){0.f, 0.f, 0.f, 0.f};

    const short* gA = xb + (size_t)m0 * KDIM;
    const short* gB = wt + (size_t)n0 * KDIM;

    stage_tile(gA, lA[0], tid);
    stage_tile(gB, lB[0], tid);
    asm volatile("s_waitcnt vmcnt(0)" ::: "memory");
    __syncthreads();

    int cur = 0;
    const int arow = (lane & 15) * 32 + (lane >> 4) * 8;
#pragma unroll 1
    for (int kt = 0; kt < KDIM / 32; ++kt) {
        if (kt + 1 < KDIM / 32) {
            stage_tile(gA + (kt + 1) * 32, lA[cur ^ 1], tid);
            stage_tile(gB + (kt + 1) * 32, lB[cur ^ 1], tid);
        }
        short8 a[4], b[4];
#pragma unroll
        for (int im = 0; im < 4; ++im)
            a[im] = *(const short8*)&lA[cur][(wm * 64 + im * 16) * 32 + arow];
#pragma unroll
        for (int in = 0; in < 4; ++in)
            b[in] = *(const short8*)&lB[cur][(wn * 64 + in * 16) * 32 + arow];
#pragma unroll
        for (int im = 0; im < 4; ++im)
#pragma unroll
            for (int in = 0; in < 4; ++in)
                acc[im][in] = __builtin_amdgcn_mfma_f32_16x16x32_bf16(a[im], b[in], acc[im][in], 0, 0, 0);
        asm volatile("s_waitcnt vmcnt(0)" ::: "memory");
        __syncthreads();
        cur ^= 1;
    }

    // epilogue: scatter to q [B,H,T,D], k [B,H,T,D], v^T [B,H,D,T]
#pragma unroll
    for (int im = 0; im < 4; ++im) {
        int t0m = m0 + wm * 64 + im * 16 + (lane >> 4) * 4;
        int b = t0m >> 11;
        int t0 = t0m & 2047;
#pragma unroll
        for (int in = 0; in < 4; ++in) {
            int col = n0 + wn * 64 + in * 16 + (lane & 15);
            int which = col >> 10;
            int h = (col >> 6) & 15;
            int d = col & 63;
            if (which == 2) {
                u16x4 pk;
#pragma unroll
                for (int r = 0; r < 4; ++r) pk[r] = f2bf(acc[im][in][r]);
                *(u16x4*)&vt[((size_t)(b * NHEAD + h) * HDIM + d) * SEQ + t0] = pk;
            } else {
                short* dst = (which == 0) ? qb : kbuf;
#pragma unroll
                for (int r = 0; r < 4; ++r)
                    dst[((size_t)(b * NHEAD + h) * SEQ + t0 + r) * HDIM + d] = (short)f2bf(acc[im][in][r]);
            }
        }
    }
}

// ---------------------------------------------------------------- flash attention
// grid (16, B*H), 256 threads = 4 waves, 16 q-rows each; fold {31-pid, pid}.
// SWAPPED QK^T: mfma(K,Q) -> S^T, each lane owns ONE q-row (col=lane&15).
// K rows fed in permuted order key(nb,m) so the lane-local P values are
// exactly the PV B-fragment -> P never leaves registers (no LDS, no shfl).
// K/V double-buffered LDS, swizzle S(r)=(r&3)^(((r>>2)&3)<<1), counted vmcnt.
#define KVB 64

__device__ __forceinline__ int swzf(int r) { return (r & 3) ^ (((r >> 2) & 3) << 1); }

__device__ __forceinline__ void stage_kv(const short* kh, const short* vh, int kb,
                                         short* lk, short* lv, int tid) {
#pragma unroll
    for (int c = 0; c < 2; ++c) {
        int row = c * 32 + (tid >> 3);               // 0..63
        int sch = (tid & 7) ^ swzf(row);             // swizzled 16B-chunk index
        const short* gk = kh + (size_t)(kb + row) * HDIM + sch * 8;
        short* lpk = lk + c * 2048 + tid * 8;        // linear: slot tid&7 of row
        __builtin_amdgcn_global_load_lds((const __attribute__((address_space(1))) void*)gk,
                                         (__attribute__((address_space(3))) void*)lpk, 16, 0, 0);
        const short* gv = vh + (size_t)row * SEQ + kb + sch * 8;   // row = d index
        short* lpv = lv + c * 2048 + tid * 8;
        __builtin_amdgcn_global_load_lds((const __attribute__((address_space(1))) void*)gv,
                                         (__attribute__((address_space(3))) void*)lpv, 16, 0, 0);
    }
}

__global__ __launch_bounds__(256) void attn_kernel(const short* __restrict__ q,
                                                   const short* __restrict__ kk,
                                                   const short* __restrict__ vtg,
                                                   float* __restrict__ out) {
    const int tid  = threadIdx.x;
    const int lane = tid & 63;
    const int wid  = tid >> 6;                       // 0..3
    const int pid = blockIdx.x;                      // 0..15
    const int bh = blockIdx.y;
    const int rbase = lane & 15;                     // my q-row within wave tile
    const int hi    = lane >> 4;

    const short* qh = q   + (size_t)bh * SEQ * HDIM;
    const short* kh = kk  + (size_t)bh * SEQ * HDIM;
    const short* vh = vtg + (size_t)bh * HDIM * SEQ;

    __shared__ short lK[2][KVB * 64];
    __shared__ short lV[2][KVB * 64];

    const float L2E = 1.4426950408889634f;
    const float C1  = 0.125f * 1.4426950408889634f;   // scale folded into exp2
    short8 vone;
#pragma unroll
    for (int j = 0; j < 8; ++j) vone[j] = (short)0x3F80;   // bf16 1.0

    const int b = bh >> 4, h = bh & 15;

#pragma unroll 1
    for (int seg = 0; seg < 2; ++seg) {
        const int qt = seg ? pid : (31 - pid);
        const int qbase = qt * 64 + wid * 16;
        const int qrow  = qbase + rbase;

        // Q fragment (B-frag: lane n=rbase holds Q[qrow][k], k = hi*8+j)
        short8 aQ[2];
#pragma unroll
        for (int c = 0; c < 2; ++c)
            aQ[c] = *(const short8*)&qh[(size_t)qrow * HDIM + c * 32 + hi * 8];

        f32x4 o[4];
#pragma unroll
        for (int i = 0; i < 4; ++i) o[i] = (f32x4){0.f, 0.f, 0.f, 0.f};
        float mrun = -INFINITY;
        float lrun = 0.f;

        const int ktiles = qt + 1;
        stage_kv(kh, vh, 0, lK[0], lV[0], tid);
        int cur = 0;
#pragma unroll 1
        for (int t = 0; t < ktiles; ++t) {
            const int kb = t * KVB;
            if (t + 1 < ktiles) {
                stage_kv(kh, vh, kb + KVB, lK[cur ^ 1], lV[cur ^ 1], tid);
                asm volatile("s_waitcnt vmcnt(4) lgkmcnt(0)" ::: "memory");
            } else {
                asm volatile("s_waitcnt vmcnt(0) lgkmcnt(0)" ::: "memory");
            }
            __builtin_amdgcn_s_barrier();
            __builtin_amdgcn_sched_barrier(0);

            if (kb < qbase + 16) {   // wave-uniform: tile not fully masked
                const short* lk = lK[cur];
                const short* lv = lV[cur];
                // ---- QK^T swapped: s[nb] = S^T block; lane col = my q-row.
                // K row for A-frag slot m: key(nb,m)=(nb&1)*32+(m>>2)*8+(nb>>1)*4+(m&3)
                f32x4 s[4];
                __builtin_amdgcn_s_setprio(1);
#pragma unroll
                for (int nb = 0; nb < 4; ++nb) {
                    int kidx = (nb & 1) * 32 + (rbase >> 2) * 8 + (nb >> 1) * 4 + (rbase & 3);
                    f32x4 a = (f32x4){0.f, 0.f, 0.f, 0.f};
#pragma unroll
                    for (int c = 0; c < 2; ++c) {
                        int slot = (c * 4 + hi) ^ swzf(kidx);
                        short8 bK = *(const short8*)&lk[kidx * 64 + slot * 8];
                        a = __builtin_amdgcn_mfma_f32_16x16x32_bf16(bK, aQ[c], a, 0, 0, 0);
                    }
                    s[nb] = a;
                }
                __builtin_amdgcn_s_setprio(0);
                // ---- causal mask (diagonal tile only; wave-uniform branch)
                // s[nb][r] is key  kb + (nb&1)*32 + hi*8 + (nb>>1)*4 + r
                if (kb + KVB - 1 > qbase) {
#pragma unroll
                    for (int nb = 0; nb < 4; ++nb) {
                        int keyb = kb + (nb & 1) * 32 + hi * 8 + (nb >> 1) * 4;
#pragma unroll
                        for (int r = 0; r < 4; ++r)
                            if (keyb + r > qrow) s[nb][r] = -1e30f;
                    }
                }
                // ---- row max: in-lane tree + 2 shfl across hi-groups
                float pm = fmaxf(fmaxf(fmaxf(s[0][0], s[0][1]), fmaxf(s[0][2], s[0][3])),
                                 fmaxf(fmaxf(s[1][0], s[1][1]), fmaxf(s[1][2], s[1][3])));
                float pm2 = fmaxf(fmaxf(fmaxf(s[2][0], s[2][1]), fmaxf(s[2][2], s[2][3])),
                                  fmaxf(fmaxf(s[3][0], s[3][1]), fmaxf(s[3][2], s[3][3])));
                pm = fmaxf(pm, pm2);
                pm = fmaxf(pm, __shfl_xor(pm, 16));
                pm = fmaxf(pm, __shfl_xor(pm, 32));
                pm *= 0.125f;
                // ---- defer-max: rescale only when some row's max grew
                if (__any(pm > mrun)) {
                    float mnew = fmaxf(mrun, pm);
                    float sf = exp2f((mrun - mnew) * L2E);
                    mrun = mnew;
                    lrun *= sf;
#pragma unroll
                    for (int dt = 0; dt < 4; ++dt)
#pragma unroll
                        for (int r = 0; r < 4; ++r) o[dt][r] *= sf;
                }
                float mterm = mrun * L2E;
                // ---- P = exp2(s*C1 - mterm) -> bf16, packed directly as PV B-frags
                short8 bp[2];
#pragma unroll
                for (int c = 0; c < 2; ++c)
#pragma unroll
                    for (int j = 0; j < 8; ++j) {
                        float p = exp2f(fmaf(s[c + (j >> 2) * 2][j & 3], C1, -mterm));
                        bp[c][j] = (short)f2bf(p);
                    }
                // ---- PV swapped: o^T[d][qrow] += V^T-frag * P^T-frag; + ones row-sum
                f32x4 osum = (f32x4){0.f, 0.f, 0.f, 0.f};
                __builtin_amdgcn_s_setprio(1);
#pragma unroll
                for (int dt = 0; dt < 4; ++dt) {
                    int d = dt * 16 + rbase;
#pragma unroll
                    for (int c = 0; c < 2; ++c) {
                        int slot = (c * 4 + hi) ^ swzf(d);
                        short8 bV = *(const short8*)&lv[d * 64 + slot * 8];
                        o[dt] = __builtin_amdgcn_mfma_f32_16x16x32_bf16(bV, bp[c], o[dt], 0, 0, 0);
                    }
                }
#pragma unroll
                for (int c = 0; c < 2; ++c)
                    osum = __builtin_amdgcn_mfma_f32_16x16x32_bf16(vone, bp[c], osum, 0, 0, 0);
                __builtin_amdgcn_s_setprio(0);
                lrun += osum[0];
            }
            __builtin_amdgcn_sched_barrier(0);
            __builtin_amdgcn_s_barrier();
            cur ^= 1;
        }

        // write out [B,T,H,D] fp32: lane owns row qrow, d = dt*16 + hi*4 + r
        float inv = 1.0f / lrun;
#pragma unroll
        for (int dt = 0; dt < 4; ++dt) {
            f32x4 ov;
#pragma unroll
            for (int r = 0; r < 4; ++r) ov[r] = o[dt][r] * inv;
            *(f32x4*)&out[((size_t)(b * SEQ + qrow) * NHEAD + h) * HDIM + dt * 16 + hi * 4] = ov;
        }
    }
}

// ---------------------------------------------------------------- launch
extern "C" void kernel_launch(void* const* d_in, const int* in_sizes, int n_in,
                              void* d_out, int out_size, void* d_ws, size_t ws_size,
                              hipStream_t stream) {
    const float* x = (const float*)d_in[0];
    const float* w = (const float*)d_in[1];
    float* out = (float*)d_out;

    char* ws = (char*)d_ws;
    short* xb   = (short*)(ws);                            // 8 MB  [M,K] bf16
    short* wt   = (short*)(ws + (size_t)8  * 1024 * 1024); // 6 MB  [N3,K] bf16
    short* qb   = (short*)(ws + (size_t)14 * 1024 * 1024); // 8 MB  [B,H,T,D]
    short* kbuf = (short*)(ws + (size_t)22 * 1024 * 1024); // 8 MB  [B,H,T,D]
    short* vt   = (short*)(ws + (size_t)30 * 1024 * 1024); // 8 MB  [B,H,D,T]

    cast_x_kernel<<<dim3(MTOT * KDIM / 4 / 256), dim3(256), 0, stream>>>(x, xb, MTOT * KDIM / 4);
    cast_wt_kernel<<<dim3(N3 / 32, KDIM / 32), dim3(256), 0, stream>>>(w, wt);
    qkv_gemm_kernel<<<dim3(N3 / 128, MTOT / 128), dim3(256), 0, stream>>>(xb, wt, qb, kbuf, vt);
    attn_kernel<<<dim3(16, BATCH * NHEAD), dim3(256), 0, stream>>>(qb, kbuf, vt, out);
}

// Round 6
// 101.674 us; speedup vs baseline: 1.2591x; 1.0724x over previous
//
#include <hip/hip_runtime.h>
#include <hip/hip_bf16.h>

// Problem constants
#define BATCH 2
#define SEQ   2048
#define EMBD  1024
#define NHEAD 16
#define HDIM  64
#define N3    3072           // 3*EMBD
#define MTOT  4096           // BATCH*SEQ
#define KDIM  1024

typedef __attribute__((ext_vector_type(8))) short  short8;   // 8 x bf16 (4 VGPRs)
typedef __attribute__((ext_vector_type(4))) short  s16x4;
typedef __attribute__((ext_vector_type(4))) float  f32x4;

__device__ __forceinline__ short f2bfs(float f) {
    return __builtin_bit_cast(short, __float2bfloat16(f));   // compiler emits v_cvt_pk_bf16_f32 for pairs
}

// ---------------------------------------------------------------- cast x -> bf16
__global__ __launch_bounds__(256) void cast_x_kernel(const float* __restrict__ x,
                                                     short* __restrict__ xb, int n4) {
    int i = blockIdx.x * 256 + threadIdx.x;
    if (i >= n4) return;
    float4 f = reinterpret_cast<const float4*>(x)[i];
    s16x4 o;
    o[0] = f2bfs(f.x); o[1] = f2bfs(f.y);
    o[2] = f2bfs(f.z); o[3] = f2bfs(f.w);
    reinterpret_cast<s16x4*>(xb)[i] = o;
}

// ------------------------------------------- cast + transpose w [K,N3] -> wt [N3,K]
__global__ __launch_bounds__(256) void cast_wt_kernel(const float* __restrict__ w,
                                                      short* __restrict__ wt) {
    __shared__ float tile[32][33];
    int n0 = blockIdx.x * 32;   // N3/32 = 96
    int k0 = blockIdx.y * 32;   // K/32  = 32
    int tx = threadIdx.x & 31;
    int ty = threadIdx.x >> 5;  // 0..7
#pragma unroll
    for (int i = 0; i < 4; ++i)
        tile[ty + i * 8][tx] = w[(size_t)(k0 + ty + i * 8) * N3 + n0 + tx];
    __syncthreads();
#pragma unroll
    for (int i = 0; i < 4; ++i)
        wt[(size_t)(n0 + ty + i * 8) * KDIM + k0 + tx] = f2bfs(tile[tx][ty + i * 8]);
}

// ---------------------------------------------------------------- QKV GEMM
// C[m,n] = sum_k xb[m,k] * wt[n,k];  M=4096, N=3072, K=1024
__device__ __forceinline__ void stage_tile(const short* gbase, short* lbase, int tid) {
#pragma unroll
    for (int c = 0; c < 2; ++c) {
        int row = c * 64 + (tid >> 2);
        int chunk = tid & 3;
        const short* gp = gbase + (size_t)row * KDIM + chunk * 8;
        short* lp = lbase + c * 2048 + tid * 8;   // bytes: c*4096 + tid*16
        __builtin_amdgcn_global_load_lds((const __attribute__((address_space(1))) void*)gp,
                                         (__attribute__((address_space(3))) void*)lp,
                                         16, 0, 0);
    }
}

__global__ __launch_bounds__(256) void qkv_gemm_kernel(const short* __restrict__ xb,
                                                       const short* __restrict__ wt,
                                                       short* __restrict__ qb,
                                                       short* __restrict__ kbuf,
                                                       short* __restrict__ vt) {
    __shared__ short lA[2][128 * 32];
    __shared__ short lB[2][128 * 32];

    const int tid  = threadIdx.x;
    const int lane = tid & 63;
    const int wid  = tid >> 6;
    const int wm = wid >> 1, wn = wid & 1;
    const int m0 = blockIdx.y * 128;
    const int n0 = blockIdx.x * 128;

    f32x4 acc[4][4];
#pragma unroll
    for (int i = 0; i < 4; ++i)
#pragma unroll
        for (int j = 0; j < 4; ++j) acc[i][j] = (f32x4){0.f, 0.f, 0.f, 0.f};

    const short* gA = xb + (size_t)m0 * KDIM;
    const short* gB = wt + (size_t)n0 * KDIM;

    stage_tile(gA, lA[0], tid);
    stage_tile(gB, lB[0], tid);
    asm volatile("s_waitcnt vmcnt(0)" ::: "memory");
    __syncthreads();

    int cur = 0;
    const int arow = (lane & 15) * 32 + (lane >> 4) * 8;
#pragma unroll 1
    for (int kt = 0; kt < KDIM / 32; ++kt) {
        if (kt + 1 < KDIM / 32) {
            stage_tile(gA + (kt + 1) * 32, lA[cur ^ 1], tid);
            stage_tile(gB + (kt + 1) * 32, lB[cur ^ 1], tid);
        }
        short8 a[4], b[4];
#pragma unroll
        for (int im = 0; im < 4; ++im)
            a[im] = *(const short8*)&lA[cur][(wm * 64 + im * 16) * 32 + arow];
#pragma unroll
        for (int in = 0; in < 4; ++in)
            b[in] = *(const short8*)&lB[cur][(wn * 64 + in * 16) * 32 + arow];
#pragma unroll
        for (int im = 0; im < 4; ++im)
#pragma unroll
            for (int in = 0; in < 4; ++in)
                acc[im][in] = __builtin_amdgcn_mfma_f32_16x16x32_bf16(a[im], b[in], acc[im][in], 0, 0, 0);
        asm volatile("s_waitcnt vmcnt(0)" ::: "memory");
        __syncthreads();
        cur ^= 1;
    }

    // epilogue: scatter to q [B,H,T,D], k [B,H,T,D], v^T [B,H,D,T]
#pragma unroll
    for (int im = 0; im < 4; ++im) {
        int t0m = m0 + wm * 64 + im * 16 + (lane >> 4) * 4;
        int b = t0m >> 11;
        int t0 = t0m & 2047;
#pragma unroll
        for (int in = 0; in < 4; ++in) {
            int col = n0 + wn * 64 + in * 16 + (lane & 15);
            int which = col >> 10;
            int h = (col >> 6) & 15;
            int d = col & 63;
            if (which == 2) {
                s16x4 pk;
#pragma unroll
                for (int r = 0; r < 4; ++r) pk[r] = f2bfs(acc[im][in][r]);
                *(s16x4*)&vt[((size_t)(b * NHEAD + h) * HDIM + d) * SEQ + t0] = pk;
            } else {
                short* dst = (which == 0) ? qb : kbuf;
#pragma unroll
                for (int r = 0; r < 4; ++r)
                    dst[((size_t)(b * NHEAD + h) * SEQ + t0 + r) * HDIM + d] = f2bfs(acc[im][in][r]);
            }
        }
    }
}

// ---------------------------------------------------------------- flash attention
// 1D grid of 512 blocks, XCD-pinned: bh%8 == lid&7 so all 16 fold-blocks of a
// head share one XCD's L2 (K/V panel 512KB; 4 heads/XCD = 2MB < 4MB L2).
// 256 threads = 4 waves, 16 q-rows each; fold {31-pid, pid}.
// SWAPPED QK^T: mfma(K,Q) -> S^T, each lane owns ONE q-row; K rows fed in
// permuted order so lane-local P values are exactly the PV B-fragment.
#define KVB 64

__device__ __forceinline__ int swzf(int r) { return (r & 3) ^ (((r >> 2) & 3) << 1); }

__device__ __forceinline__ void stage_kv(const short* kh, const short* vh, int kb,
                                         short* lk, short* lv, int tid) {
#pragma unroll
    for (int c = 0; c < 2; ++c) {
        int row = c * 32 + (tid >> 3);               // 0..63
        int sch = (tid & 7) ^ swzf(row);             // swizzled 16B-chunk index
        const short* gk = kh + (size_t)(kb + row) * HDIM + sch * 8;
        short* lpk = lk + c * 2048 + tid * 8;        // linear: slot tid&7 of row
        __builtin_amdgcn_global_load_lds((const __attribute__((address_space(1))) void*)gk,
                                         (__attribute__((address_space(3))) void*)lpk, 16, 0, 0);
        const short* gv = vh + (size_t)row * SEQ + kb + sch * 8;   // row = d index
        short* lpv = lv + c * 2048 + tid * 8;
        __builtin_amdgcn_global_load_lds((const __attribute__((address_space(1))) void*)gv,
                                         (__attribute__((address_space(3))) void*)lpv, 16, 0, 0);
    }
}

__global__ __launch_bounds__(256) void attn_kernel(const short* __restrict__ q,
                                                   const short* __restrict__ kk,
                                                   const short* __restrict__ vtg,
                                                   float* __restrict__ out) {
    const int tid  = threadIdx.x;
    const int lane = tid & 63;
    const int wid  = tid >> 6;                       // 0..3
    const int lid  = blockIdx.x;                     // 0..511
    const int xcd  = lid & 7;
    const int rest = lid >> 3;
    const int pid  = rest & 15;                      // 0..15
    const int bh   = (rest >> 4) * 8 + xcd;          // 0..31, pinned to XCD
    const int rbase = lane & 15;                     // my q-row within wave tile
    const int hi    = lane >> 4;

    const short* qh = q   + (size_t)bh * SEQ * HDIM;
    const short* kh = kk  + (size_t)bh * SEQ * HDIM;
    const short* vh = vtg + (size_t)bh * HDIM * SEQ;

    __shared__ short lK[2][KVB * 64];
    __shared__ short lV[2][KVB * 64];

    const float L2E = 1.4426950408889634f;
    const float C1  = 0.125f * 1.4426950408889634f;   // scale folded into exp2
    short8 vone;
#pragma unroll
    for (int j = 0; j < 8; ++j) vone[j] = (short)0x3F80;   // bf16 1.0

    const int b = bh >> 4, h = bh & 15;

#pragma unroll 1
    for (int seg = 0; seg < 2; ++seg) {
        const int qt = seg ? pid : (31 - pid);
        const int qbase = qt * 64 + wid * 16;
        const int qrow  = qbase + rbase;

        // Q fragment (B-frag: lane n=rbase holds Q[qrow][k], k = hi*8+j)
        short8 aQ[2];
#pragma unroll
        for (int c = 0; c < 2; ++c)
            aQ[c] = *(const short8*)&qh[(size_t)qrow * HDIM + c * 32 + hi * 8];

        f32x4 o[4];
#pragma unroll
        for (int i = 0; i < 4; ++i) o[i] = (f32x4){0.f, 0.f, 0.f, 0.f};
        float mrun = -INFINITY;
        float lrun = 0.f;

        const int ktiles = qt + 1;
        stage_kv(kh, vh, 0, lK[0], lV[0], tid);
        int cur = 0;
#pragma unroll 1
        for (int t = 0; t < ktiles; ++t) {
            const int kb = t * KVB;
            if (t + 1 < ktiles) {
                stage_kv(kh, vh, kb + KVB, lK[cur ^ 1], lV[cur ^ 1], tid);
                asm volatile("s_waitcnt vmcnt(4) lgkmcnt(0)" ::: "memory");
            } else {
                asm volatile("s_waitcnt vmcnt(0) lgkmcnt(0)" ::: "memory");
            }
            __builtin_amdgcn_s_barrier();
            __builtin_amdgcn_sched_barrier(0);

            if (kb < qbase + 16) {   // wave-uniform: tile not fully masked
                const short* lk = lK[cur];
                const short* lv = lV[cur];
                // ---- QK^T swapped: s[nb] = S^T block; lane col = my q-row.
                // K row for A-frag slot m: key(nb,m)=(nb&1)*32+(m>>2)*8+(nb>>1)*4+(m&3)
                f32x4 s[4];
                __builtin_amdgcn_s_setprio(1);
#pragma unroll
                for (int nb = 0; nb < 4; ++nb) {
                    int kidx = (nb & 1) * 32 + (rbase >> 2) * 8 + (nb >> 1) * 4 + (rbase & 3);
                    f32x4 a = (f32x4){0.f, 0.f, 0.f, 0.f};
#pragma unroll
                    for (int c = 0; c < 2; ++c) {
                        int slot = (c * 4 + hi) ^ swzf(kidx);
                        short8 bK = *(const short8*)&lk[kidx * 64 + slot * 8];
                        a = __builtin_amdgcn_mfma_f32_16x16x32_bf16(bK, aQ[c], a, 0, 0, 0);
                    }
                    s[nb] = a;
                }
                __builtin_amdgcn_s_setprio(0);
                // ---- causal mask (diagonal tile only; wave-uniform branch)
                // s[nb][r] is key  kb + (nb&1)*32 + hi*8 + (nb>>1)*4 + r
                if (kb + KVB - 1 > qbase) {
#pragma unroll
                    for (int nb = 0; nb < 4; ++nb) {
                        int keyb = kb + (nb & 1) * 32 + hi * 8 + (nb >> 1) * 4;
#pragma unroll
                        for (int r = 0; r < 4; ++r)
                            if (keyb + r > qrow) s[nb][r] = -1e30f;
                    }
                }
                // ---- row max: in-lane tree + 2 shfl across hi-groups
                float pm = fmaxf(fmaxf(fmaxf(s[0][0], s[0][1]), fmaxf(s[0][2], s[0][3])),
                                 fmaxf(fmaxf(s[1][0], s[1][1]), fmaxf(s[1][2], s[1][3])));
                float pm2 = fmaxf(fmaxf(fmaxf(s[2][0], s[2][1]), fmaxf(s[2][2], s[2][3])),
                                  fmaxf(fmaxf(s[3][0], s[3][1]), fmaxf(s[3][2], s[3][3])));
                pm = fmaxf(pm, pm2);
                pm = fmaxf(pm, __shfl_xor(pm, 16));
                pm = fmaxf(pm, __shfl_xor(pm, 32));
                pm *= 0.125f;
                // ---- defer-max (T13, THR=8): rescale only on growth beyond headroom
                if (__any(pm > mrun + 8.0f)) {
                    float mnew = fmaxf(mrun, pm);
                    float sf = exp2f((mrun - mnew) * L2E);
                    mrun = mnew;
                    lrun *= sf;
#pragma unroll
                    for (int dt = 0; dt < 4; ++dt)
#pragma unroll
                        for (int r = 0; r < 4; ++r) o[dt][r] *= sf;
                }
                float mterm = mrun * L2E;
                // ---- P = exp2(s*C1 - mterm) -> bf16 (packed cvt), as PV B-frags
                short8 bp[2];
#pragma unroll
                for (int c = 0; c < 2; ++c)
#pragma unroll
                    for (int j = 0; j < 8; ++j) {
                        float p = exp2f(fmaf(s[c + (j >> 2) * 2][j & 3], C1, -mterm));
                        bp[c][j] = f2bfs(p);
                    }
                // ---- PV swapped: o^T[d][qrow] += V^T-frag * P^T-frag; + ones row-sum
                f32x4 osum = (f32x4){0.f, 0.f, 0.f, 0.f};
                __builtin_amdgcn_s_setprio(1);
#pragma unroll
                for (int dt = 0; dt < 4; ++dt) {
                    int d = dt * 16 + rbase;
#pragma unroll
                    for (int c = 0; c < 2; ++c) {
                        int slot = (c * 4 + hi) ^ swzf(d);
                        short8 bV = *(const short8*)&lv[d * 64 + slot * 8];
                        o[dt] = __builtin_amdgcn_mfma_f32_16x16x32_bf16(bV, bp[c], o[dt], 0, 0, 0);
                    }
                }
#pragma unroll
                for (int c = 0; c < 2; ++c)
                    osum = __builtin_amdgcn_mfma_f32_16x16x32_bf16(vone, bp[c], osum, 0, 0, 0);
                __builtin_amdgcn_s_setprio(0);
                lrun += osum[0];
            }
            __builtin_amdgcn_sched_barrier(0);
            __builtin_amdgcn_s_barrier();
            cur ^= 1;
        }

        // write out [B,T,H,D] fp32: lane owns row qrow, d = dt*16 + hi*4 + r
        float inv = 1.0f / lrun;
#pragma unroll
        for (int dt = 0; dt < 4; ++dt) {
            f32x4 ov;
#pragma unroll
            for (int r = 0; r < 4; ++r) ov[r] = o[dt][r] * inv;
            *(f32x4*)&out[((size_t)(b * SEQ + qrow) * NHEAD + h) * HDIM + dt * 16 + hi * 4] = ov;
        }
    }
}

// ---------------------------------------------------------------- launch
extern "C" void kernel_launch(void* const* d_in, const int* in_sizes, int n_in,
                              void* d_out, int out_size, void* d_ws, size_t ws_size,
                              hipStream_t stream) {
    const float* x = (const float*)d_in[0];
    const float* w = (const float*)d_in[1];
    float* out = (float*)d_out;

    char* ws = (char*)d_ws;
    short* xb   = (short*)(ws);                            // 8 MB  [M,K] bf16
    short* wt   = (short*)(ws + (size_t)8  * 1024 * 1024); // 6 MB  [N3,K] bf16
    short* qb   = (short*)(ws + (size_t)14 * 1024 * 1024); // 8 MB  [B,H,T,D]
    short* kbuf = (short*)(ws + (size_t)22 * 1024 * 1024); // 8 MB  [B,H,T,D]
    short* vt   = (short*)(ws + (size_t)30 * 1024 * 1024); // 8 MB  [B,H,D,T]

    cast_x_kernel<<<dim3(MTOT * KDIM / 4 / 256), dim3(256), 0, stream>>>(x, xb, MTOT * KDIM / 4);
    cast_wt_kernel<<<dim3(N3 / 32, KDIM / 32), dim3(256), 0, stream>>>(w, wt);
    qkv_gemm_kernel<<<dim3(N3 / 128, MTOT / 128), dim3(256), 0, stream>>>(xb, wt, qb, kbuf, vt);
    attn_kernel<<<dim3(512), dim3(256), 0, stream>>>(qb, kbuf, vt, out);
}

// Round 7
// 96.873 us; speedup vs baseline: 1.3215x; 1.0496x over previous
//
#include <hip/hip_runtime.h>
#include <hip/hip_bf16.h>

// Problem constants
#define BATCH 2
#define SEQ   2048
#define EMBD  1024
#define NHEAD 16
#define HDIM  64
#define N3    3072           // 3*EMBD
#define MTOT  4096           // BATCH*SEQ
#define KDIM  1024

typedef __attribute__((ext_vector_type(8))) short  short8;   // 8 x bf16 (4 VGPRs)
typedef __attribute__((ext_vector_type(4))) short  s16x4;
typedef __attribute__((ext_vector_type(4))) float  f32x4;

__device__ __forceinline__ short f2bfs(float f) {
    return __builtin_bit_cast(short, __float2bfloat16(f));   // compiler emits v_cvt_pk_bf16_f32 for pairs
}

// ---------------------------------------------------------------- cast x -> bf16
__global__ __launch_bounds__(256) void cast_x_kernel(const float* __restrict__ x,
                                                     short* __restrict__ xb, int n4) {
    int i = blockIdx.x * 256 + threadIdx.x;
    if (i >= n4) return;
    float4 f = reinterpret_cast<const float4*>(x)[i];
    s16x4 o;
    o[0] = f2bfs(f.x); o[1] = f2bfs(f.y);
    o[2] = f2bfs(f.z); o[3] = f2bfs(f.w);
    reinterpret_cast<s16x4*>(xb)[i] = o;
}

// ------------------------------------------- cast + transpose w [K,N3] -> wt [N3,K]
__global__ __launch_bounds__(256) void cast_wt_kernel(const float* __restrict__ w,
                                                      short* __restrict__ wt) {
    __shared__ float tile[32][33];
    int n0 = blockIdx.x * 32;   // N3/32 = 96
    int k0 = blockIdx.y * 32;   // K/32  = 32
    int tx = threadIdx.x & 31;
    int ty = threadIdx.x >> 5;  // 0..7
#pragma unroll
    for (int i = 0; i < 4; ++i)
        tile[ty + i * 8][tx] = w[(size_t)(k0 + ty + i * 8) * N3 + n0 + tx];
    __syncthreads();
#pragma unroll
    for (int i = 0; i < 4; ++i)
        wt[(size_t)(n0 + ty + i * 8) * KDIM + k0 + tx] = f2bfs(tile[tx][ty + i * 8]);
}

// ---------------------------------------------------------------- QKV GEMM
// C[m,n] = sum_k xb[m,k] * wt[n,k];  M=4096, N=3072, K=1024
__device__ __forceinline__ void stage_tile(const short* gbase, short* lbase, int tid) {
#pragma unroll
    for (int c = 0; c < 2; ++c) {
        int row = c * 64 + (tid >> 2);
        int chunk = tid & 3;
        const short* gp = gbase + (size_t)row * KDIM + chunk * 8;
        short* lp = lbase + c * 2048 + tid * 8;   // bytes: c*4096 + tid*16
        __builtin_amdgcn_global_load_lds((const __attribute__((address_space(1))) void*)gp,
                                         (__attribute__((address_space(3))) void*)lp,
                                         16, 0, 0);
    }
}

__global__ __launch_bounds__(256) void qkv_gemm_kernel(const short* __restrict__ xb,
                                                       const short* __restrict__ wt,
                                                       short* __restrict__ qb,
                                                       short* __restrict__ kbuf,
                                                       short* __restrict__ vt) {
    __shared__ short lA[2][128 * 32];
    __shared__ short lB[2][128 * 32];

    const int tid  = threadIdx.x;
    const int lane = tid & 63;
    const int wid  = tid >> 6;
    const int wm = wid >> 1, wn = wid & 1;
    const int m0 = blockIdx.y * 128;
    const int n0 = blockIdx.x * 128;

    f32x4 acc[4][4];
#pragma unroll
    for (int i = 0; i < 4; ++i)
#pragma unroll
        for (int j = 0; j < 4; ++j) acc[i][j] = (f32x4){0.f, 0.f, 0.f, 0.f};

    const short* gA = xb + (size_t)m0 * KDIM;
    const short* gB = wt + (size_t)n0 * KDIM;

    stage_tile(gA, lA[0], tid);
    stage_tile(gB, lB[0], tid);
    asm volatile("s_waitcnt vmcnt(0)" ::: "memory");
    __syncthreads();

    int cur = 0;
    const int arow = (lane & 15) * 32 + (lane >> 4) * 8;
#pragma unroll 1
    for (int kt = 0; kt < KDIM / 32; ++kt) {
        if (kt + 1 < KDIM / 32) {
            stage_tile(gA + (kt + 1) * 32, lA[cur ^ 1], tid);
            stage_tile(gB + (kt + 1) * 32, lB[cur ^ 1], tid);
        }
        short8 a[4], b[4];
#pragma unroll
        for (int im = 0; im < 4; ++im)
            a[im] = *(const short8*)&lA[cur][(wm * 64 + im * 16) * 32 + arow];
#pragma unroll
        for (int in = 0; in < 4; ++in)
            b[in] = *(const short8*)&lB[cur][(wn * 64 + in * 16) * 32 + arow];
#pragma unroll
        for (int im = 0; im < 4; ++im)
#pragma unroll
            for (int in = 0; in < 4; ++in)
                acc[im][in] = __builtin_amdgcn_mfma_f32_16x16x32_bf16(a[im], b[in], acc[im][in], 0, 0, 0);
        asm volatile("s_waitcnt vmcnt(0)" ::: "memory");
        __syncthreads();
        cur ^= 1;
    }

    // epilogue: scatter to q [B,H,T,D], k [B,H,T,D], v^T [B,H,D,T]
#pragma unroll
    for (int im = 0; im < 4; ++im) {
        int t0m = m0 + wm * 64 + im * 16 + (lane >> 4) * 4;
        int b = t0m >> 11;
        int t0 = t0m & 2047;
#pragma unroll
        for (int in = 0; in < 4; ++in) {
            int col = n0 + wn * 64 + in * 16 + (lane & 15);
            int which = col >> 10;
            int h = (col >> 6) & 15;
            int d = col & 63;
            if (which == 2) {
                s16x4 pk;
#pragma unroll
                for (int r = 0; r < 4; ++r) pk[r] = f2bfs(acc[im][in][r]);
                *(s16x4*)&vt[((size_t)(b * NHEAD + h) * HDIM + d) * SEQ + t0] = pk;
            } else {
                short* dst = (which == 0) ? qb : kbuf;
#pragma unroll
                for (int r = 0; r < 4; ++r)
                    dst[((size_t)(b * NHEAD + h) * SEQ + t0 + r) * HDIM + d] = f2bfs(acc[im][in][r]);
            }
        }
    }
}

// ---------------------------------------------------------------- flash attention
// 1024 blocks = 4 blocks/CU. Block -> (xcd, batch, slot): qt chosen so that under
// round-robin CU fill each CU's 4 blocks sum to exactly 66 kv-tile iterations:
//   batch0: qt=31-u, b1: 16+u, b2: 15-u, b3: u   (u = slot>>2)
// Longest batch dispatched first (LPT fallback). Each CU slot keeps ONE head
// (hrank=slot&3) for all 4 of its blocks -> L2 locality. bh%8 == xcd (pinning).
// 256 threads = 4 waves, 16 q-rows each. SWAPPED QK^T: mfma(K,Q) -> S^T, lane
// owns one q-row; K rows fed permuted so lane-local P is exactly the PV B-frag.
#define KVB 64

__device__ __forceinline__ int swzf(int r) { return (r & 3) ^ (((r >> 2) & 3) << 1); }

__device__ __forceinline__ void stage_kv(const short* kh, const short* vh, int kb,
                                         short* lk, short* lv, int tid) {
#pragma unroll
    for (int c = 0; c < 2; ++c) {
        int row = c * 32 + (tid >> 3);               // 0..63
        int sch = (tid & 7) ^ swzf(row);             // swizzled 16B-chunk index
        const short* gk = kh + (size_t)(kb + row) * HDIM + sch * 8;
        short* lpk = lk + c * 2048 + tid * 8;        // linear: slot tid&7 of row
        __builtin_amdgcn_global_load_lds((const __attribute__((address_space(1))) void*)gk,
                                         (__attribute__((address_space(3))) void*)lpk, 16, 0, 0);
        const short* gv = vh + (size_t)row * SEQ + kb + sch * 8;   // row = d index
        short* lpv = lv + c * 2048 + tid * 8;
        __builtin_amdgcn_global_load_lds((const __attribute__((address_space(1))) void*)gv,
                                         (__attribute__((address_space(3))) void*)lpv, 16, 0, 0);
    }
}

__global__ __launch_bounds__(256) void attn_kernel(const short* __restrict__ q,
                                                   const short* __restrict__ kk,
                                                   const short* __restrict__ vtg,
                                                   float* __restrict__ out) {
    const int tid  = threadIdx.x;
    const int lane = tid & 63;
    const int wid  = tid >> 6;                       // 0..3
    const int lid  = blockIdx.x;                     // 0..1023
    const int xcd  = lid & 7;
    const int rest = lid >> 3;                       // 0..127
    const int batch = rest >> 5;                     // 0..3 (dispatch order)
    const int slot  = rest & 31;                     // CU slot within XCD
    const int u     = slot >> 2;                     // 0..7
    const int hrank = slot & 3;                      // head rank on this CU
    const int qt = (batch == 0) ? 31 - u : (batch == 1) ? 16 + u
                 : (batch == 2) ? 15 - u : u;
    const int bh = hrank * 8 + xcd;                  // 0..31, pinned to XCD
    const int rbase = lane & 15;                     // my q-row within wave tile
    const int hi    = lane >> 4;

    const short* qh = q   + (size_t)bh * SEQ * HDIM;
    const short* kh = kk  + (size_t)bh * SEQ * HDIM;
    const short* vh = vtg + (size_t)bh * HDIM * SEQ;

    __shared__ short lK[2][KVB * 64];
    __shared__ short lV[2][KVB * 64];

    const float L2E = 1.4426950408889634f;
    const float C1  = 0.125f * 1.4426950408889634f;   // scale folded into exp2
    short8 vone;
#pragma unroll
    for (int j = 0; j < 8; ++j) vone[j] = (short)0x3F80;   // bf16 1.0

    const int b = bh >> 4, h = bh & 15;

    const int qbase = qt * 64 + wid * 16;
    const int qrow  = qbase + rbase;

    // Q fragment (B-frag: lane n=rbase holds Q[qrow][k], k = hi*8+j)
    short8 aQ[2];
#pragma unroll
    for (int c = 0; c < 2; ++c)
        aQ[c] = *(const short8*)&qh[(size_t)qrow * HDIM + c * 32 + hi * 8];

    f32x4 o[4];
#pragma unroll
    for (int i = 0; i < 4; ++i) o[i] = (f32x4){0.f, 0.f, 0.f, 0.f};
    float mrun = -INFINITY;
    float lrun = 0.f;

    const int ktiles = qt + 1;
    stage_kv(kh, vh, 0, lK[0], lV[0], tid);
    int cur = 0;
#pragma unroll 1
    for (int t = 0; t < ktiles; ++t) {
        const int kb = t * KVB;
        if (t + 1 < ktiles) {
            stage_kv(kh, vh, kb + KVB, lK[cur ^ 1], lV[cur ^ 1], tid);
            asm volatile("s_waitcnt vmcnt(4) lgkmcnt(0)" ::: "memory");
        } else {
            asm volatile("s_waitcnt vmcnt(0) lgkmcnt(0)" ::: "memory");
        }
        __builtin_amdgcn_s_barrier();
        __builtin_amdgcn_sched_barrier(0);

        if (kb < qbase + 16) {   // wave-uniform: tile not fully masked
            const short* lk = lK[cur];
            const short* lv = lV[cur];
            // ---- QK^T swapped: s[nb] = S^T block; lane col = my q-row.
            // K row for A-frag slot m: key(nb,m)=(nb&1)*32+(m>>2)*8+(nb>>1)*4+(m&3)
            f32x4 s[4];
            __builtin_amdgcn_s_setprio(1);
#pragma unroll
            for (int nb = 0; nb < 4; ++nb) {
                int kidx = (nb & 1) * 32 + (rbase >> 2) * 8 + (nb >> 1) * 4 + (rbase & 3);
                f32x4 a = (f32x4){0.f, 0.f, 0.f, 0.f};
#pragma unroll
                for (int c = 0; c < 2; ++c) {
                    int slot2 = (c * 4 + hi) ^ swzf(kidx);
                    short8 bK = *(const short8*)&lk[kidx * 64 + slot2 * 8];
                    a = __builtin_amdgcn_mfma_f32_16x16x32_bf16(bK, aQ[c], a, 0, 0, 0);
                }
                s[nb] = a;
            }
            __builtin_amdgcn_s_setprio(0);
            // ---- causal mask (diagonal tile only; wave-uniform branch)
            // s[nb][r] is key  kb + (nb&1)*32 + hi*8 + (nb>>1)*4 + r
            if (kb + KVB - 1 > qbase) {
#pragma unroll
                for (int nb = 0; nb < 4; ++nb) {
                    int keyb = kb + (nb & 1) * 32 + hi * 8 + (nb >> 1) * 4;
#pragma unroll
                    for (int r = 0; r < 4; ++r)
                        if (keyb + r > qrow) s[nb][r] = -1e30f;
                }
            }
            // ---- row max: in-lane tree + 2 shfl across hi-groups
            float pm = fmaxf(fmaxf(fmaxf(s[0][0], s[0][1]), fmaxf(s[0][2], s[0][3])),
                             fmaxf(fmaxf(s[1][0], s[1][1]), fmaxf(s[1][2], s[1][3])));
            float pm2 = fmaxf(fmaxf(fmaxf(s[2][0], s[2][1]), fmaxf(s[2][2], s[2][3])),
                              fmaxf(fmaxf(s[3][0], s[3][1]), fmaxf(s[3][2], s[3][3])));
            pm = fmaxf(pm, pm2);
            pm = fmaxf(pm, __shfl_xor(pm, 16));
            pm = fmaxf(pm, __shfl_xor(pm, 32));
            pm *= 0.125f;
            // ---- defer-max (T13, THR=8): rescale only on growth beyond headroom
            if (__any(pm > mrun + 8.0f)) {
                float mnew = fmaxf(mrun, pm);
                float sf = exp2f((mrun - mnew) * L2E);
                mrun = mnew;
                lrun *= sf;
#pragma unroll
                for (int dt = 0; dt < 4; ++dt)
#pragma unroll
                    for (int r = 0; r < 4; ++r) o[dt][r] *= sf;
            }
            float mterm = mrun * L2E;
            // ---- P = exp2(s*C1 - mterm) -> bf16 (packed cvt), as PV B-frags
            short8 bp[2];
#pragma unroll
            for (int c = 0; c < 2; ++c)
#pragma unroll
                for (int j = 0; j < 8; ++j) {
                    float p = exp2f(fmaf(s[c + (j >> 2) * 2][j & 3], C1, -mterm));
                    bp[c][j] = f2bfs(p);
                }
            // ---- PV swapped: o^T[d][qrow] += V^T-frag * P^T-frag; + ones row-sum
            f32x4 osum = (f32x4){0.f, 0.f, 0.f, 0.f};
            __builtin_amdgcn_s_setprio(1);
#pragma unroll
            for (int dt = 0; dt < 4; ++dt) {
                int d = dt * 16 + rbase;
#pragma unroll
                for (int c = 0; c < 2; ++c) {
                    int slot2 = (c * 4 + hi) ^ swzf(d);
                    short8 bV = *(const short8*)&lv[d * 64 + slot2 * 8];
                    o[dt] = __builtin_amdgcn_mfma_f32_16x16x32_bf16(bV, bp[c], o[dt], 0, 0, 0);
                }
            }
#pragma unroll
            for (int c = 0; c < 2; ++c)
                osum = __builtin_amdgcn_mfma_f32_16x16x32_bf16(vone, bp[c], osum, 0, 0, 0);
            __builtin_amdgcn_s_setprio(0);
            lrun += osum[0];
        }
        __builtin_amdgcn_sched_barrier(0);
        __builtin_amdgcn_s_barrier();
        cur ^= 1;
    }

    // write out [B,T,H,D] fp32: lane owns row qrow, d = dt*16 + hi*4 + r
    float inv = 1.0f / lrun;
#pragma unroll
    for (int dt = 0; dt < 4; ++dt) {
        f32x4 ov;
#pragma unroll
        for (int r = 0; r < 4; ++r) ov[r] = o[dt][r] * inv;
        *(f32x4*)&out[((size_t)(b * SEQ + qrow) * NHEAD + h) * HDIM + dt * 16 + hi * 4] = ov;
    }
}

// ---------------------------------------------------------------- launch
extern "C" void kernel_launch(void* const* d_in, const int* in_sizes, int n_in,
                              void* d_out, int out_size, void* d_ws, size_t ws_size,
                              hipStream_t stream) {
    const float* x = (const float*)d_in[0];
    const float* w = (const float*)d_in[1];
    float* out = (float*)d_out;

    char* ws = (char*)d_ws;
    short* xb   = (short*)(ws);                            // 8 MB  [M,K] bf16
    short* wt   = (short*)(ws + (size_t)8  * 1024 * 1024); // 6 MB  [N3,K] bf16
    short* qb   = (short*)(ws + (size_t)14 * 1024 * 1024); // 8 MB  [B,H,T,D]
    short* kbuf = (short*)(ws + (size_t)22 * 1024 * 1024); // 8 MB  [B,H,T,D]
    short* vt   = (short*)(ws + (size_t)30 * 1024 * 1024); // 8 MB  [B,H,D,T]

    cast_x_kernel<<<dim3(MTOT * KDIM / 4 / 256), dim3(256), 0, stream>>>(x, xb, MTOT * KDIM / 4);
    cast_wt_kernel<<<dim3(N3 / 32, KDIM / 32), dim3(256), 0, stream>>>(w, wt);
    qkv_gemm_kernel<<<dim3(N3 / 128, MTOT / 128), dim3(256), 0, stream>>>(xb, wt, qb, kbuf, vt);
    attn_kernel<<<dim3(1024), dim3(256), 0, stream>>>(qb, kbuf, vt, out);
}

// Round 8
// 96.127 us; speedup vs baseline: 1.3317x; 1.0078x over previous
//
#include <hip/hip_runtime.h>
#include <hip/hip_bf16.h>

// Problem constants
#define BATCH 2
#define SEQ   2048
#define EMBD  1024
#define NHEAD 16
#define HDIM  64
#define N3    3072           // 3*EMBD
#define MTOT  4096           // BATCH*SEQ
#define KDIM  1024

typedef __attribute__((ext_vector_type(8))) short  short8;   // 8 x bf16 (4 VGPRs)
typedef __attribute__((ext_vector_type(4))) short  s16x4;
typedef __attribute__((ext_vector_type(4))) float  f32x4;

__device__ __forceinline__ short f2bfs(float f) {
    return __builtin_bit_cast(short, __float2bfloat16(f));   // compiler emits v_cvt_pk_bf16_f32 for pairs
}

// ---------------------------------------------------------------- cast x -> bf16
__global__ __launch_bounds__(256) void cast_x_kernel(const float* __restrict__ x,
                                                     short* __restrict__ xb, int n4) {
    int i = blockIdx.x * 256 + threadIdx.x;
    if (i >= n4) return;
    float4 f = reinterpret_cast<const float4*>(x)[i];
    s16x4 o;
    o[0] = f2bfs(f.x); o[1] = f2bfs(f.y);
    o[2] = f2bfs(f.z); o[3] = f2bfs(f.w);
    reinterpret_cast<s16x4*>(xb)[i] = o;
}

// ------------------------------------------- cast + transpose w [K,N3] -> wt [N3,K]
__global__ __launch_bounds__(256) void cast_wt_kernel(const float* __restrict__ w,
                                                      short* __restrict__ wt) {
    __shared__ float tile[32][33];
    int n0 = blockIdx.x * 32;   // N3/32 = 96
    int k0 = blockIdx.y * 32;   // K/32  = 32
    int tx = threadIdx.x & 31;
    int ty = threadIdx.x >> 5;  // 0..7
#pragma unroll
    for (int i = 0; i < 4; ++i)
        tile[ty + i * 8][tx] = w[(size_t)(k0 + ty + i * 8) * N3 + n0 + tx];
    __syncthreads();
#pragma unroll
    for (int i = 0; i < 4; ++i)
        wt[(size_t)(n0 + ty + i * 8) * KDIM + k0 + tx] = f2bfs(tile[tx][ty + i * 8]);
}

// ---------------------------------------------------------------- QKV GEMM
// C[m,n] = sum_k xb[m,k] * wt[n,k];  M=4096, N=3072, K=1024
// LDS XOR-swizzle (T2): tile rows stride 64B -> unswizzled b128 reads hit only
// bank-groups {0,16} (8-way). Store global k-chunk (slot ^ ((row>>1)&3)) at
// linear slot; read slot = hi ^ ((row>>1)&3). 8 consecutive lanes then cover
// all 8 bank-groups (conflict-free).
__device__ __forceinline__ void stage_tile(const short* gbase, short* lbase, int tid) {
#pragma unroll
    for (int c = 0; c < 2; ++c) {
        int row = c * 64 + (tid >> 2);
        int chunk = (tid & 3) ^ ((row >> 1) & 3);    // inverse-swizzled source
        const short* gp = gbase + (size_t)row * KDIM + chunk * 8;
        short* lp = lbase + c * 2048 + tid * 8;      // linear dest: row, slot tid&3
        __builtin_amdgcn_global_load_lds((const __attribute__((address_space(1))) void*)gp,
                                         (__attribute__((address_space(3))) void*)lp,
                                         16, 0, 0);
    }
}

__global__ __launch_bounds__(256) void qkv_gemm_kernel(const short* __restrict__ xb,
                                                       const short* __restrict__ wt,
                                                       short* __restrict__ qb,
                                                       short* __restrict__ kbuf,
                                                       short* __restrict__ vt) {
    __shared__ short lA[2][128 * 32];
    __shared__ short lB[2][128 * 32];

    const int tid  = threadIdx.x;
    const int lane = tid & 63;
    const int wid  = tid >> 6;
    const int wm = wid >> 1, wn = wid & 1;
    // XCD-aware bijective swizzle (768 = 8 XCDs x 96): each XCD owns 4 m-rows
    const int lid = blockIdx.x;
    const int swz = (lid & 7) * 96 + (lid >> 3);
    const int m0 = (swz / 24) * 128;
    const int n0 = (swz % 24) * 128;

    f32x4 acc[4][4];
#pragma unroll
    for (int i = 0; i < 4; ++i)
#pragma unroll
        for (int j = 0; j < 4; ++j) acc[i][j] = (f32x4){0.f, 0.f, 0.f, 0.f};

    const short* gA = xb + (size_t)m0 * KDIM;
    const short* gB = wt + (size_t)n0 * KDIM;

    stage_tile(gA, lA[0], tid);
    stage_tile(gB, lB[0], tid);
    asm volatile("s_waitcnt vmcnt(0)" ::: "memory");
    __syncthreads();

    int cur = 0;
    // swizzled fragment slot: hi ^ ((row>>1)&3), row bits from lane&15
    const int arow = (lane & 15) * 32 + (((lane >> 4) ^ ((lane >> 1) & 3)) * 8);
#pragma unroll 1
    for (int kt = 0; kt < KDIM / 32; ++kt) {
        if (kt + 1 < KDIM / 32) {
            stage_tile(gA + (kt + 1) * 32, lA[cur ^ 1], tid);
            stage_tile(gB + (kt + 1) * 32, lB[cur ^ 1], tid);
        }
        short8 a[4], b[4];
#pragma unroll
        for (int im = 0; im < 4; ++im)
            a[im] = *(const short8*)&lA[cur][(wm * 64 + im * 16) * 32 + arow];
#pragma unroll
        for (int in = 0; in < 4; ++in)
            b[in] = *(const short8*)&lB[cur][(wn * 64 + in * 16) * 32 + arow];
#pragma unroll
        for (int im = 0; im < 4; ++im)
#pragma unroll
            for (int in = 0; in < 4; ++in)
                acc[im][in] = __builtin_amdgcn_mfma_f32_16x16x32_bf16(a[im], b[in], acc[im][in], 0, 0, 0);
        asm volatile("s_waitcnt vmcnt(0)" ::: "memory");
        __syncthreads();
        cur ^= 1;
    }

    // epilogue: scatter to q [B,H,T,D], k [B,H,T,D], v^T [B,H,D,T]
#pragma unroll
    for (int im = 0; im < 4; ++im) {
        int t0m = m0 + wm * 64 + im * 16 + (lane >> 4) * 4;
        int b = t0m >> 11;
        int t0 = t0m & 2047;
#pragma unroll
        for (int in = 0; in < 4; ++in) {
            int col = n0 + wn * 64 + in * 16 + (lane & 15);
            int which = col >> 10;
            int h = (col >> 6) & 15;
            int d = col & 63;
            if (which == 2) {
                s16x4 pk;
#pragma unroll
                for (int r = 0; r < 4; ++r) pk[r] = f2bfs(acc[im][in][r]);
                *(s16x4*)&vt[((size_t)(b * NHEAD + h) * HDIM + d) * SEQ + t0] = pk;
            } else {
                short* dst = (which == 0) ? qb : kbuf;
#pragma unroll
                for (int r = 0; r < 4; ++r)
                    dst[((size_t)(b * NHEAD + h) * SEQ + t0 + r) * HDIM + d] = f2bfs(acc[im][in][r]);
            }
        }
    }
}

// ---------------------------------------------------------------- flash attention
// 1024 blocks = 4 blocks/CU. Block -> (xcd, batch, slot): qt chosen so that under
// round-robin CU fill each CU's 4 blocks sum to exactly 66 kv-tile iterations:
//   batch0: qt=31-u, b1: 16+u, b2: 15-u, b3: u   (u = slot>>2)
// Longest batch dispatched first (LPT fallback). Each CU slot keeps ONE head
// (hrank=slot&3) for all 4 of its blocks -> L2 locality. bh%8 == xcd (pinning).
// 256 threads = 4 waves, 16 q-rows each. SWAPPED QK^T: mfma(K,Q) -> S^T, lane
// owns one q-row; K rows fed permuted so lane-local P is exactly the PV B-frag.
#define KVB 64

__device__ __forceinline__ int swzf(int r) { return (r & 3) ^ (((r >> 2) & 3) << 1); }

__device__ __forceinline__ void stage_kv(const short* kh, const short* vh, int kb,
                                         short* lk, short* lv, int tid) {
#pragma unroll
    for (int c = 0; c < 2; ++c) {
        int row = c * 32 + (tid >> 3);               // 0..63
        int sch = (tid & 7) ^ swzf(row);             // swizzled 16B-chunk index
        const short* gk = kh + (size_t)(kb + row) * HDIM + sch * 8;
        short* lpk = lk + c * 2048 + tid * 8;        // linear: slot tid&7 of row
        __builtin_amdgcn_global_load_lds((const __attribute__((address_space(1))) void*)gk,
                                         (__attribute__((address_space(3))) void*)lpk, 16, 0, 0);
        const short* gv = vh + (size_t)row * SEQ + kb + sch * 8;   // row = d index
        short* lpv = lv + c * 2048 + tid * 8;
        __builtin_amdgcn_global_load_lds((const __attribute__((address_space(1))) void*)gv,
                                         (__attribute__((address_space(3))) void*)lpv, 16, 0, 0);
    }
}

__global__ __launch_bounds__(256) void attn_kernel(const short* __restrict__ q,
                                                   const short* __restrict__ kk,
                                                   const short* __restrict__ vtg,
                                                   float* __restrict__ out) {
    const int tid  = threadIdx.x;
    const int lane = tid & 63;
    const int wid  = tid >> 6;                       // 0..3
    const int lid  = blockIdx.x;                     // 0..1023
    const int xcd  = lid & 7;
    const int rest = lid >> 3;                       // 0..127
    const int batch = rest >> 5;                     // 0..3 (dispatch order)
    const int slot  = rest & 31;                     // CU slot within XCD
    const int u     = slot >> 2;                     // 0..7
    const int hrank = slot & 3;                      // head rank on this CU
    const int qt = (batch == 0) ? 31 - u : (batch == 1) ? 16 + u
                 : (batch == 2) ? 15 - u : u;
    const int bh = hrank * 8 + xcd;                  // 0..31, pinned to XCD
    const int rbase = lane & 15;                     // my q-row within wave tile
    const int hi    = lane >> 4;

    const short* qh = q   + (size_t)bh * SEQ * HDIM;
    const short* kh = kk  + (size_t)bh * SEQ * HDIM;
    const short* vh = vtg + (size_t)bh * HDIM * SEQ;

    __shared__ short lK[2][KVB * 64];
    __shared__ short lV[2][KVB * 64];

    const float L2E = 1.4426950408889634f;
    const float C1  = 0.125f * 1.4426950408889634f;   // scale folded into exp2
    short8 vone;
#pragma unroll
    for (int j = 0; j < 8; ++j) vone[j] = (short)0x3F80;   // bf16 1.0

    const int b = bh >> 4, h = bh & 15;

    const int qbase = qt * 64 + wid * 16;
    const int qrow  = qbase + rbase;

    // Q fragment (B-frag: lane n=rbase holds Q[qrow][k], k = hi*8+j)
    short8 aQ[2];
#pragma unroll
    for (int c = 0; c < 2; ++c)
        aQ[c] = *(const short8*)&qh[(size_t)qrow * HDIM + c * 32 + hi * 8];

    f32x4 o[4];
#pragma unroll
    for (int i = 0; i < 4; ++i) o[i] = (f32x4){0.f, 0.f, 0.f, 0.f};
    float mrun = -INFINITY;
    float lrun = 0.f;

    const int ktiles = qt + 1;
    stage_kv(kh, vh, 0, lK[0], lV[0], tid);
    int cur = 0;
#pragma unroll 1
    for (int t = 0; t < ktiles; ++t) {
        const int kb = t * KVB;
        if (t + 1 < ktiles) {
            stage_kv(kh, vh, kb + KVB, lK[cur ^ 1], lV[cur ^ 1], tid);
            asm volatile("s_waitcnt vmcnt(4) lgkmcnt(0)" ::: "memory");
        } else {
            asm volatile("s_waitcnt vmcnt(0) lgkmcnt(0)" ::: "memory");
        }
        __builtin_amdgcn_s_barrier();
        __builtin_amdgcn_sched_barrier(0);

        if (kb < qbase + 16) {   // wave-uniform: tile not fully masked
            const short* lk = lK[cur];
            const short* lv = lV[cur];
            // ---- QK^T swapped: s[nb] = S^T block; lane col = my q-row.
            // K row for A-frag slot m: key(nb,m)=(nb&1)*32+(m>>2)*8+(nb>>1)*4+(m&3)
            f32x4 s[4];
            __builtin_amdgcn_s_setprio(1);
#pragma unroll
            for (int nb = 0; nb < 4; ++nb) {
                int kidx = (nb & 1) * 32 + (rbase >> 2) * 8 + (nb >> 1) * 4 + (rbase & 3);
                f32x4 a = (f32x4){0.f, 0.f, 0.f, 0.f};
#pragma unroll
                for (int c = 0; c < 2; ++c) {
                    int slot2 = (c * 4 + hi) ^ swzf(kidx);
                    short8 bK = *(const short8*)&lk[kidx * 64 + slot2 * 8];
                    a = __builtin_amdgcn_mfma_f32_16x16x32_bf16(bK, aQ[c], a, 0, 0, 0);
                }
                s[nb] = a;
            }
            __builtin_amdgcn_s_setprio(0);
            // ---- causal mask (diagonal tile only; wave-uniform branch)
            // s[nb][r] is key  kb + (nb&1)*32 + hi*8 + (nb>>1)*4 + r
            if (kb + KVB - 1 > qbase) {
#pragma unroll
                for (int nb = 0; nb < 4; ++nb) {
                    int keyb = kb + (nb & 1) * 32 + hi * 8 + (nb >> 1) * 4;
#pragma unroll
                    for (int r = 0; r < 4; ++r)
                        if (keyb + r > qrow) s[nb][r] = -1e30f;
                }
            }
            // ---- row max: in-lane tree + 2 shfl across hi-groups
            float pm = fmaxf(fmaxf(fmaxf(s[0][0], s[0][1]), fmaxf(s[0][2], s[0][3])),
                             fmaxf(fmaxf(s[1][0], s[1][1]), fmaxf(s[1][2], s[1][3])));
            float pm2 = fmaxf(fmaxf(fmaxf(s[2][0], s[2][1]), fmaxf(s[2][2], s[2][3])),
                              fmaxf(fmaxf(s[3][0], s[3][1]), fmaxf(s[3][2], s[3][3])));
            pm = fmaxf(pm, pm2);
            pm = fmaxf(pm, __shfl_xor(pm, 16));
            pm = fmaxf(pm, __shfl_xor(pm, 32));
            pm *= 0.125f;
            // ---- defer-max (T13, THR=8): rescale only on growth beyond headroom
            if (__any(pm > mrun + 8.0f)) {
                float mnew = fmaxf(mrun, pm);
                float sf = exp2f((mrun - mnew) * L2E);
                mrun = mnew;
                lrun *= sf;
#pragma unroll
                for (int dt = 0; dt < 4; ++dt)
#pragma unroll
                    for (int r = 0; r < 4; ++r) o[dt][r] *= sf;
            }
            float mterm = mrun * L2E;
            // ---- P = exp2(s*C1 - mterm) -> bf16 (packed cvt), as PV B-frags
            short8 bp[2];
#pragma unroll
            for (int c = 0; c < 2; ++c)
#pragma unroll
                for (int j = 0; j < 8; ++j) {
                    float p = exp2f(fmaf(s[c + (j >> 2) * 2][j & 3], C1, -mterm));
                    bp[c][j] = f2bfs(p);
                }
            // ---- PV swapped: o^T[d][qrow] += V^T-frag * P^T-frag; + ones row-sum
            f32x4 osum = (f32x4){0.f, 0.f, 0.f, 0.f};
            __builtin_amdgcn_s_setprio(1);
#pragma unroll
            for (int dt = 0; dt < 4; ++dt) {
                int d = dt * 16 + rbase;
#pragma unroll
                for (int c = 0; c < 2; ++c) {
                    int slot2 = (c * 4 + hi) ^ swzf(d);
                    short8 bV = *(const short8*)&lv[d * 64 + slot2 * 8];
                    o[dt] = __builtin_amdgcn_mfma_f32_16x16x32_bf16(bV, bp[c], o[dt], 0, 0, 0);
                }
            }
#pragma unroll
            for (int c = 0; c < 2; ++c)
                osum = __builtin_amdgcn_mfma_f32_16x16x32_bf16(vone, bp[c], osum, 0, 0, 0);
            __builtin_amdgcn_s_setprio(0);
            lrun += osum[0];
        }
        __builtin_amdgcn_sched_barrier(0);
        __builtin_amdgcn_s_barrier();
        cur ^= 1;
    }

    // write out [B,T,H,D] fp32: lane owns row qrow, d = dt*16 + hi*4 + r
    float inv = 1.0f / lrun;
#pragma unroll
    for (int dt = 0; dt < 4; ++dt) {
        f32x4 ov;
#pragma unroll
        for (int r = 0; r < 4; ++r) ov[r] = o[dt][r] * inv;
        *(f32x4*)&out[((size_t)(b * SEQ + qrow) * NHEAD + h) * HDIM + dt * 16 + hi * 4] = ov;
    }
}

// ---------------------------------------------------------------- launch
extern "C" void kernel_launch(void* const* d_in, const int* in_sizes, int n_in,
                              void* d_out, int out_size, void* d_ws, size_t ws_size,
                              hipStream_t stream) {
    const float* x = (const float*)d_in[0];
    const float* w = (const float*)d_in[1];
    float* out = (float*)d_out;

    char* ws = (char*)d_ws;
    short* xb   = (short*)(ws);                            // 8 MB  [M,K] bf16
    short* wt   = (short*)(ws + (size_t)8  * 1024 * 1024); // 6 MB  [N3,K] bf16
    short* qb   = (short*)(ws + (size_t)14 * 1024 * 1024); // 8 MB  [B,H,T,D]
    short* kbuf = (short*)(ws + (size_t)22 * 1024 * 1024); // 8 MB  [B,H,T,D]
    short* vt   = (short*)(ws + (size_t)30 * 1024 * 1024); // 8 MB  [B,H,D,T]

    cast_x_kernel<<<dim3(MTOT * KDIM / 4 / 256), dim3(256), 0, stream>>>(x, xb, MTOT * KDIM / 4);
    cast_wt_kernel<<<dim3(N3 / 32, KDIM / 32), dim3(256), 0, stream>>>(w, wt);
    qkv_gemm_kernel<<<dim3(768), dim3(256), 0, stream>>>(xb, wt, qb, kbuf, vt);
    attn_kernel<<<dim3(1024), dim3(256), 0, stream>>>(qb, kbuf, vt, out);
}